// Round 9
// baseline (145.658 us; speedup 1.0000x reference)
//
#include <hip/hip_runtime.h>
#include <cstdint>

#define NTOK 65536
#define DIM 240
#define KP 256
#define NMETA 576
#define NGB 512          // gating blocks (128 tokens each)

typedef short bf16x8 __attribute__((ext_vector_type(8)));
typedef float f32x16 __attribute__((ext_vector_type(16)));

union U16B { uint4 u; bf16x8 v; };

__device__ __forceinline__ unsigned short f2bf(float x) {
  unsigned int u = __float_as_uint(x);
  u += 0x7fffu + ((u >> 16) & 1u);     // RNE
  return (unsigned short)(u >> 16);
}

// DPP move helpers (VALU pipe, zero LDS ops). 0xB1 = quad_perm xor1,
// 0x4E = quad_perm xor2, 0x128 = row_ror:8 (== xor8 within a 16-lane row).
template<int CTRL>
__device__ __forceinline__ float dppf(float v) {
  return __int_as_float(__builtin_amdgcn_update_dpp(0, __float_as_int(v), CTRL, 0xF, 0xF, true));
}
template<int CTRL>
__device__ __forceinline__ unsigned dppu(unsigned v) {
  return (unsigned)__builtin_amdgcn_update_dpp(0, (int)v, CTRL, 0xF, 0xF, true);
}
// packed (float value | 3-bit expert idx in mantissa LSBs) compare: larger value
// wins; exact tie -> lower idx wins (matches lax.top_k first-index rule).
__device__ __forceinline__ bool pgt(unsigned a, unsigned b) {
  float fa = __uint_as_float(a & ~7u), fb = __uint_as_float(b & ~7u);
  return (fa != fb) ? (fa > fb) : ((a & 7u) < (b & 7u));
}
template<int CTRL>
__device__ __forceinline__ void top2round(unsigned& a1, unsigned& a2) {
  unsigned b1 = dppu<CTRL>(a1), b2 = dppu<CTRL>(a2);
  bool g = pgt(a1, b1);
  unsigned n1 = g ? a1 : b1;
  unsigned lo = g ? b1 : a1;                 // loser of the firsts
  unsigned m2 = pgt(a2, b2) ? a2 : b2;
  a2 = pgt(lo, m2) ? lo : m2;
  a1 = n1;
}

// ---------------- kernel 1: pack expert weights to bf16 [8][256][256], bias fused at k=240
__global__ __launch_bounds__(256) void prep_w(const float* __restrict__ ew,
                                              const float* __restrict__ eb,
                                              unsigned short* __restrict__ Wb) {
  int idx = blockIdx.x * 256 + threadIdx.x;     // 131072 threads, 4 k's each
  int k0 = (idx & 63) << 2;
  int n  = (idx >> 6) & 255;
  int e  = idx >> 14;
  ushort4 v = {0, 0, 0, 0};
  if (n < DIM) {
    float f0 = 0.f, f1 = 0.f, f2 = 0.f, f3 = 0.f;
    const float* wrow = ew + (e * DIM + n) * DIM;
    if (k0 < DIM) { f0 = wrow[k0]; f1 = wrow[k0 + 1]; f2 = wrow[k0 + 2]; f3 = wrow[k0 + 3]; }
    else if (k0 == DIM) { f0 = eb[e * DIM + n]; }   // bias column
    v.x = f2bf(f0); v.y = f2bf(f1); v.z = f2bf(f2); v.w = f2bf(f3);
  }
  *(ushort4*)&Wb[(size_t)idx * 4] = v;
}

// ---------------- kernel 2: gating, DPP-dominant reduce (3 LDS-pipe ops/token)
__global__ __launch_bounds__(512) void gating(const float* __restrict__ x,
                                              const float* __restrict__ gw,
                                              const float* __restrict__ gb,
                                              unsigned short* __restrict__ xb,
                                              unsigned char* __restrict__ pairid,
                                              float2* __restrict__ wpair,
                                              int* __restrict__ hist2d) {
  __shared__ __align__(16) float gwT[8][DIM];
  __shared__ int hist[64];
  for (int i = threadIdx.x; i < 8 * DIM; i += 512) gwT[i & 7][i >> 3] = gw[i];
  if (threadIdx.x < 64) hist[threadIdx.x] = 0;
  __syncthreads();
  const int lane = threadIdx.x & 63;
  const int w = threadIdx.x >> 6;
  const bool act = lane < 60;
  float4 g[8];
#pragma unroll
  for (int e = 0; e < 8; ++e)
    g[e] = act ? *(const float4*)(&gwT[e][lane * 4]) : make_float4(0.f, 0.f, 0.f, 0.f);
  // after the halving reduce, this lane holds the sum for expert elane:
  const int elane = 4 * (lane & 1) + 2 * ((lane >> 1) & 1) + ((lane >> 3) & 1);
  const float gbl = gb[elane];
  const int tbase = blockIdx.x * 128 + w * 16;
  for (int it = 0; it < 16; ++it) {
    const int t = tbase + it;
    float4 xv = act ? *(const float4*)(x + (size_t)t * DIM + lane * 4)
                    : make_float4(0.f, 0.f, 0.f, 0.f);
    float p[8];
#pragma unroll
    for (int e = 0; e < 8; ++e)
      p[e] = xv.x * g[e].x + xv.y * g[e].y + xv.z * g[e].z + xv.w * g[e].w;
    // halving butterfly: mask1 (quad_perm), mask2 (quad_perm), mask8 (row_ror:8)
    float q4[4];
#pragma unroll
    for (int i = 0; i < 4; ++i) {
      float lo = p[i] + dppf<0xB1>(p[i]);
      float hi = p[i + 4] + dppf<0xB1>(p[i + 4]);
      q4[i] = (lane & 1) ? hi : lo;
    }
    float q2[2];
#pragma unroll
    for (int i = 0; i < 2; ++i) {
      float lo = q4[i] + dppf<0x4E>(q4[i]);
      float hi = q4[i + 2] + dppf<0x4E>(q4[i + 2]);
      q2[i] = (lane & 2) ? hi : lo;
    }
    {
      float lo = q2[0] + dppf<0x128>(q2[0]);
      float hi = q2[1] + dppf<0x128>(q2[1]);
      float s = (lane & 8) ? hi : lo;
      // complete reduction over remaining masks 4,16,32 (LDS pipe: 3 ops)
      s += __shfl_xor(s, 4);
      s += __shfl_xor(s, 16);
      s += __shfl_xor(s, 32);
      s += gbl;                                 // logit for expert elane
      // all-DPP top-2 over the 8 classes (bits 0,1,3 of lane)
      unsigned a1 = (__float_as_uint(s) & ~7u) | (unsigned)elane;
      unsigned a2 = (0xFF800000u & ~7u) | 7u;   // -inf
      top2round<0xB1>(a1, a2);
      top2round<0x4E>(a1, a2);
      top2round<0x128>(a1, a2);
      const int i1 = a1 & 7, i2 = a2 & 7;
      const float l1 = __uint_as_float(a1 & ~7u), l2 = __uint_as_float(a2 & ~7u);
      const float qq = expf(l2 - l1);
      const float w1 = 1.f / (1.f + qq);        // weight of argmax
      const float w2 = qq / (1.f + qq);         // weight of runner-up
      ushort4 v = {0, 0, 0, 0};
      if (act) { v.x = f2bf(xv.x); v.y = f2bf(xv.y); v.z = f2bf(xv.z); v.w = f2bf(xv.w); }
      else if (lane == 60) v.x = 0x3F80;        // x[240] = 1.0 (bias column)
      *(ushort4*)(xb + (size_t)t * KP + lane * 4) = v;
      if (lane == 0) {
        const int ea = (i1 < i2) ? i1 : i2, eb2 = (i1 < i2) ? i2 : i1;
        const float wa = (i1 < i2) ? w1 : w2, wb2 = (i1 < i2) ? w2 : w1;
        const int pp = ea * 8 + eb2;
        pairid[t] = (unsigned char)pp;
        wpair[t] = make_float2(wa, wb2);
        atomicAdd(&hist[pp], 1);                // LDS only
      }
    }
  }
  __syncthreads();
  if (threadIdx.x < 64) hist2d[blockIdx.x * 64 + threadIdx.x] = hist[threadIdx.x];
}

// ---------------- kernel 3: per-pair exclusive scan over 512 block-hists (64 blocks)
__global__ __launch_bounds__(512) void scan1_k(const int* __restrict__ hist2d,
                                               int* __restrict__ lbase2d,
                                               int* __restrict__ cnt) {
  __shared__ int s[NGB];
  const int p = blockIdx.x, tid = threadIdx.x;
  const int v = hist2d[tid * 64 + p];
  s[tid] = v;
  __syncthreads();
  for (int off = 1; off < NGB; off <<= 1) {
    int tv = (tid >= off) ? s[tid - off] : 0;
    __syncthreads();
    s[tid] += tv;
    __syncthreads();
  }
  lbase2d[tid * 64 + p] = s[tid] - v;            // exclusive within pair
  if (tid == NGB - 1) cnt[p] = s[tid];
}

// ---------------- kernel 4: pair starts + tile meta (128-token tiles; 1 block, 64 threads)
__global__ void scan2_k(const int* __restrict__ cnt, int* __restrict__ start,
                        int4* __restrict__ meta) {
  __shared__ int sc[64], sstart[64], stile[64], stot;
  const int tid = threadIdx.x;
  sc[tid] = cnt[tid];
  __syncthreads();
  if (tid == 0) {
    int a = 0, ta = 0;
    for (int p = 0; p < 64; ++p) { sstart[p] = a; stile[p] = ta; a += sc[p]; ta += (sc[p] + 127) >> 7; }
    stot = ta;
  }
  __syncthreads();
  start[tid] = sstart[tid];
  const int c = sc[tid], e0 = tid >> 3, e1 = tid & 7;
  for (int i = 0; (i << 7) < c; ++i)
    meta[stile[tid] + i] = make_int4(e0, e1, sstart[tid] + (i << 7), min(128, c - (i << 7)));
  for (int j = stot + tid; j < NMETA; j += 64)
    meta[j] = make_int4(0, 0, 0, 0);
}

// ---------------- kernel 5: route only (no data copy): wsorted/tokord
__global__ __launch_bounds__(128) void route_k(const unsigned char* __restrict__ pairid,
                                               const float2* __restrict__ wpair,
                                               const int* __restrict__ start,
                                               const int* __restrict__ lbase2d,
                                               float2* __restrict__ wsorted,
                                               int* __restrict__ tokord) {
  __shared__ int lcnt[64];
  const int b = blockIdx.x, tid = threadIdx.x;
  if (tid < 64) lcnt[tid] = 0;
  __syncthreads();
  const int t = b * 128 + tid;
  const int p = pairid[t];
  const int rank = atomicAdd(&lcnt[p], 1);       // LDS only
  const int pos = start[p] + lbase2d[b * 64 + p] + rank;
  wsorted[pos] = wpair[t];
  tokord[pos] = t;
}

// ---------------- kernel 6: pair-sparse GEMM, barrier-free W-streaming.
// Block: 128 tok (A in LDS, gathered once) x 128 cols (half of 256) x 2 experts.
// Per wave (8 = 4 row x 2 col groups): 16 k-steps, each = 1 ds_read_b128 (A) +
// 4 global 16B W loads (L1/L2-hot) + 4 MFMAs into dual accumulators. No loop barriers.
#define GLDS16(g, l)                                                        \
  __builtin_amdgcn_global_load_lds(                                         \
      (__attribute__((address_space(1))) unsigned int*)(g),                 \
      (__attribute__((address_space(3))) unsigned int*)(l), 16, 0, 0)

__global__ __launch_bounds__(512, 4) void moe_gemm_pair(const unsigned short* __restrict__ xb,
                                                        const unsigned short* __restrict__ Wb,
                                                        const float2* __restrict__ wsorted,
                                                        const int* __restrict__ tokord,
                                                        const int4* __restrict__ meta,
                                                        float* __restrict__ out) {
  extern __shared__ __align__(16) char smem[];
  // A: [granule g=0..31][row=0..127][16B] = 64K; ptok @65536; wab @66048
  int* ptok = (int*)(smem + 65536);
  float2* wab = (float2*)(smem + 66048);

  const int4 m = meta[blockIdx.x >> 1];
  const int n = m.w;
  if (n == 0) return;
  const int ch = blockIdx.x & 1;                 // column half
  const int tid = threadIdx.x, lane = tid & 63, wid = tid >> 6;
  const int wr = wid >> 1, wc = wid & 1;         // 4 row-groups x 2 col-groups
  const int l31 = lane & 31, hi = lane >> 5;

  if (tid < 128) {
    const int idx = m.z + (tid < n ? tid : n - 1);
    ptok[tid] = tokord[idx];
    wab[tid] = wsorted[idx];
  }
  __syncthreads();

  // gather-stage the full A tile once: 128 rows x 512B
  {
    const int row = tid & 127, gb4 = tid >> 7;   // granule base 0..3
    const char* src = (const char*)xb + (size_t)ptok[row] * 512 + gb4 * 16;
    char* dst = smem + (gb4 * 128 + row) * 16;
#pragma unroll
    for (int j = 0; j < 8; ++j)                  // granule g = gb4 + 4j
      GLDS16(src + j * 64, dst + j * 8192);
  }
  __syncthreads();                               // the only other barrier

  const int colb = ch * 128 + wc * 64 + l31;     // cf=0 column of this lane
  const char* pw0 = (const char*)Wb + (size_t)m.x * 131072 + (size_t)colb * 512 + hi * 16;
  const char* pw1 = (const char*)Wb + (size_t)m.y * 131072 + (size_t)colb * 512 + hi * 16;
  const char* pa  = smem + hi * 2048 + (wr * 32 + l31) * 16;   // + ks*4096

  f32x16 accA[2] = {}, accB[2] = {};
#pragma unroll
  for (int ks = 0; ks < 16; ++ks) {
    U16B a; a.u = *(const uint4*)(pa + ks * 4096);
    U16B b00, b01, b10, b11;
    b00.u = *(const uint4*)(pw0 + ks * 32);
    b01.u = *(const uint4*)(pw0 + 16384 + ks * 32);     // cf=1 (+32 cols)
    b10.u = *(const uint4*)(pw1 + ks * 32);
    b11.u = *(const uint4*)(pw1 + 16384 + ks * 32);
    accA[0] = __builtin_amdgcn_mfma_f32_32x32x16_bf16(a.v, b00.v, accA[0], 0, 0, 0);
    accA[1] = __builtin_amdgcn_mfma_f32_32x32x16_bf16(a.v, b01.v, accA[1], 0, 0, 0);
    accB[0] = __builtin_amdgcn_mfma_f32_32x32x16_bf16(a.v, b10.v, accB[0], 0, 0, 0);
    accB[1] = __builtin_amdgcn_mfma_f32_32x32x16_bf16(a.v, b11.v, accB[1], 0, 0, 0);
  }

  // epilogue: out[tok, col] = wa*P_A + wb*P_B
#pragma unroll
  for (int cf = 0; cf < 2; ++cf) {
    const int col = colb + cf * 32;
    if (col < DIM) {
#pragma unroll
      for (int r = 0; r < 16; ++r) {
        const int rw = wr * 32 + (r & 3) + ((r >> 2) << 3) + (hi << 2);
        if (rw < n) {
          const float2 w2 = wab[rw];
          out[(size_t)ptok[rw] * DIM + col] = w2.x * accA[cf][r] + w2.y * accB[cf][r];
        }
      }
    }
  }
}

extern "C" void kernel_launch(void* const* d_in, const int* in_sizes, int n_in,
                              void* d_out, int out_size, void* d_ws, size_t ws_size,
                              hipStream_t stream) {
  const float* x  = (const float*)d_in[0];
  const float* gw = (const float*)d_in[1];
  const float* gb = (const float*)d_in[2];
  const float* ew = (const float*)d_in[3];
  const float* eb = (const float*)d_in[4];
  float* out = (float*)d_out;

  // workspace layout (~36.3 MB)
  char* ws = (char*)d_ws;
  unsigned short* Wb   = (unsigned short*)ws;                          // 1 MB
  unsigned short* xb   = (unsigned short*)(ws + 1048576);              // 32 MB (unsorted bf16 [NTOK][256])
  float2*         wpr  = (float2*)(ws + 34603008);                     // 512 KB
  float2*         wsr  = (float2*)(ws + 35127296);                     // 512 KB
  int*            tord = (int*)(ws + 35651584);                        // 256 KB
  unsigned char*  pid  = (unsigned char*)(ws + 35913728);              // 64 KB
  int*            h2d  = (int*)(ws + 35979264);                        // 128 KB
  int*            lb2d = (int*)(ws + 36110336);                        // 128 KB
  int*            cnt  = (int*)(ws + 36241408);                        // 256 B
  int*            strt = (int*)(ws + 36241664);                        // 256 B
  int4*           meta = (int4*)(ws + 36241920);                       // 9.2 KB

  hipFuncSetAttribute((const void*)moe_gemm_pair, hipFuncAttributeMaxDynamicSharedMemorySize, 67584);

  prep_w<<<512, 256, 0, stream>>>(ew, eb, Wb);
  gating<<<NGB, 512, 0, stream>>>(x, gw, gb, xb, pid, wpr, h2d);
  scan1_k<<<64, NGB, 0, stream>>>(h2d, lb2d, cnt);
  scan2_k<<<1, 64, 0, stream>>>(cnt, strt, meta);
  route_k<<<NGB, 128, 0, stream>>>(pid, wpr, strt, lb2d, wsr, tord);
  moe_gemm_pair<<<2 * NMETA, 512, 67584, stream>>>(xb, Wb, wsr, tord, meta, out);
}

// Round 10
// 107.454 us; speedup vs baseline: 1.3555x; 1.3555x over previous
//
#include <hip/hip_runtime.h>
#include <cstdint>

#define NTOK 65536
#define DIM 240
#define KP 256
#define NMETA 576
#define NGB 512          // gating blocks (128 tokens each)

typedef short bf16x8 __attribute__((ext_vector_type(8)));
typedef float f32x16 __attribute__((ext_vector_type(16)));

union U16B { uint4 u; bf16x8 v; };

__device__ __forceinline__ unsigned short f2bf(float x) {
  unsigned int u = __float_as_uint(x);
  u += 0x7fffu + ((u >> 16) & 1u);     // RNE
  return (unsigned short)(u >> 16);
}

// DPP move helpers (VALU pipe, zero LDS ops). 0xB1 = quad_perm xor1,
// 0x4E = quad_perm xor2, 0x128 = row_ror:8 (== xor8 within a 16-lane row).
template<int CTRL>
__device__ __forceinline__ float dppf(float v) {
  return __int_as_float(__builtin_amdgcn_update_dpp(0, __float_as_int(v), CTRL, 0xF, 0xF, true));
}
template<int CTRL>
__device__ __forceinline__ unsigned dppu(unsigned v) {
  return (unsigned)__builtin_amdgcn_update_dpp(0, (int)v, CTRL, 0xF, 0xF, true);
}
// packed (float value | 3-bit expert idx in mantissa LSBs) compare: larger value
// wins; exact tie -> lower idx wins (matches lax.top_k first-index rule).
__device__ __forceinline__ bool pgt(unsigned a, unsigned b) {
  float fa = __uint_as_float(a & ~7u), fb = __uint_as_float(b & ~7u);
  return (fa != fb) ? (fa > fb) : ((a & 7u) < (b & 7u));
}
template<int CTRL>
__device__ __forceinline__ void top2round(unsigned& a1, unsigned& a2) {
  unsigned b1 = dppu<CTRL>(a1), b2 = dppu<CTRL>(a2);
  bool g = pgt(a1, b1);
  unsigned n1 = g ? a1 : b1;
  unsigned lo = g ? b1 : a1;                 // loser of the firsts
  unsigned m2 = pgt(a2, b2) ? a2 : b2;
  a2 = pgt(lo, m2) ? lo : m2;
  a1 = n1;
}

// ---------------- kernel 1: pack expert weights to bf16 [8][256][256]
__global__ __launch_bounds__(256) void prep_w(const float* __restrict__ ew,
                                              const float* __restrict__ eb,
                                              unsigned short* __restrict__ Wb) {
  int idx = blockIdx.x * 256 + threadIdx.x;     // 131072 threads, 4 k's each
  int k0 = (idx & 63) << 2;
  int n  = (idx >> 6) & 255;
  int e  = idx >> 14;
  ushort4 v = {0, 0, 0, 0};
  if (n < DIM && k0 < DIM) {
    const float* wrow = ew + (e * DIM + n) * DIM;
    v.x = f2bf(wrow[k0]); v.y = f2bf(wrow[k0 + 1]);
    v.z = f2bf(wrow[k0 + 2]); v.w = f2bf(wrow[k0 + 3]);
  }
  *(ushort4*)&Wb[(size_t)idx * 4] = v;
}

// ---------------- kernel 2: gating, DPP-dominant reduce (3 LDS-pipe ops/token)
__global__ __launch_bounds__(512) void gating(const float* __restrict__ x,
                                              const float* __restrict__ gw,
                                              const float* __restrict__ gb,
                                              unsigned short* __restrict__ xb,
                                              unsigned char* __restrict__ pairid,
                                              float2* __restrict__ wpair,
                                              int* __restrict__ hist2d) {
  __shared__ __align__(16) float gwT[8][DIM];
  __shared__ int hist[64];
  for (int i = threadIdx.x; i < 8 * DIM; i += 512) gwT[i & 7][i >> 3] = gw[i];
  if (threadIdx.x < 64) hist[threadIdx.x] = 0;
  __syncthreads();
  const int lane = threadIdx.x & 63;
  const int w = threadIdx.x >> 6;
  const bool act = lane < 60;
  float4 g[8];
#pragma unroll
  for (int e = 0; e < 8; ++e)
    g[e] = act ? *(const float4*)(&gwT[e][lane * 4]) : make_float4(0.f, 0.f, 0.f, 0.f);
  // after the halving reduce, this lane holds the sum for expert elane:
  const int elane = 4 * (lane & 1) + 2 * ((lane >> 1) & 1) + ((lane >> 3) & 1);
  const float gbl = gb[elane];
  const int tbase = blockIdx.x * 128 + w * 16;
  for (int it = 0; it < 16; ++it) {
    const int t = tbase + it;
    float4 xv = act ? *(const float4*)(x + (size_t)t * DIM + lane * 4)
                    : make_float4(0.f, 0.f, 0.f, 0.f);
    float p[8];
#pragma unroll
    for (int e = 0; e < 8; ++e)
      p[e] = xv.x * g[e].x + xv.y * g[e].y + xv.z * g[e].z + xv.w * g[e].w;
    // halving butterfly: mask1 (quad_perm), mask2 (quad_perm), mask8 (row_ror:8)
    float q4[4];
#pragma unroll
    for (int i = 0; i < 4; ++i) {
      float lo = p[i] + dppf<0xB1>(p[i]);
      float hi = p[i + 4] + dppf<0xB1>(p[i + 4]);
      q4[i] = (lane & 1) ? hi : lo;
    }
    float q2[2];
#pragma unroll
    for (int i = 0; i < 2; ++i) {
      float lo = q4[i] + dppf<0x4E>(q4[i]);
      float hi = q4[i + 2] + dppf<0x4E>(q4[i + 2]);
      q2[i] = (lane & 2) ? hi : lo;
    }
    {
      float lo = q2[0] + dppf<0x128>(q2[0]);
      float hi = q2[1] + dppf<0x128>(q2[1]);
      float s = (lane & 8) ? hi : lo;
      // complete reduction over remaining masks 4,16,32 (LDS pipe: 3 ops)
      s += __shfl_xor(s, 4);
      s += __shfl_xor(s, 16);
      s += __shfl_xor(s, 32);
      s += gbl;                                 // logit for expert elane
      // all-DPP top-2 over the 8 classes (bits 0,1,3 of lane)
      unsigned a1 = (__float_as_uint(s) & ~7u) | (unsigned)elane;
      unsigned a2 = (0xFF800000u & ~7u) | 7u;   // -inf
      top2round<0xB1>(a1, a2);
      top2round<0x4E>(a1, a2);
      top2round<0x128>(a1, a2);
      const int i1 = a1 & 7, i2 = a2 & 7;
      const float l1 = __uint_as_float(a1 & ~7u), l2 = __uint_as_float(a2 & ~7u);
      const float qq = expf(l2 - l1);
      const float w1 = 1.f / (1.f + qq);        // weight of argmax
      const float w2 = qq / (1.f + qq);         // weight of runner-up
      ushort4 v = {0, 0, 0, 0};
      if (act) { v.x = f2bf(xv.x); v.y = f2bf(xv.y); v.z = f2bf(xv.z); v.w = f2bf(xv.w); }
      *(ushort4*)(xb + (size_t)t * KP + lane * 4) = v;
      if (lane == 0) {
        const int ea = (i1 < i2) ? i1 : i2, eb2 = (i1 < i2) ? i2 : i1;
        const float wa = (i1 < i2) ? w1 : w2, wb2 = (i1 < i2) ? w2 : w1;
        const int pp = ea * 8 + eb2;
        pairid[t] = (unsigned char)pp;
        wpair[t] = make_float2(wa, wb2);
        atomicAdd(&hist[pp], 1);                // LDS only
      }
    }
  }
  __syncthreads();
  if (threadIdx.x < 64) hist2d[blockIdx.x * 64 + threadIdx.x] = hist[threadIdx.x];
}

// ---------------- kernel 3: per-pair exclusive scan over 512 block-hists (64 blocks)
__global__ __launch_bounds__(512) void scan1_k(const int* __restrict__ hist2d,
                                               int* __restrict__ lbase2d,
                                               int* __restrict__ cnt) {
  __shared__ int s[NGB];
  const int p = blockIdx.x, tid = threadIdx.x;
  const int v = hist2d[tid * 64 + p];
  s[tid] = v;
  __syncthreads();
  for (int off = 1; off < NGB; off <<= 1) {
    int tv = (tid >= off) ? s[tid - off] : 0;
    __syncthreads();
    s[tid] += tv;
    __syncthreads();
  }
  lbase2d[tid * 64 + p] = s[tid] - v;            // exclusive within pair
  if (tid == NGB - 1) cnt[p] = s[tid];
}

// ---------------- kernel 4: pair starts + tile meta (128-token tiles; 1 block, 64 threads)
__global__ void scan2_k(const int* __restrict__ cnt, int* __restrict__ start,
                        int4* __restrict__ meta) {
  __shared__ int sc[64], sstart[64], stile[64], stot;
  const int tid = threadIdx.x;
  sc[tid] = cnt[tid];
  __syncthreads();
  if (tid == 0) {
    int a = 0, ta = 0;
    for (int p = 0; p < 64; ++p) { sstart[p] = a; stile[p] = ta; a += sc[p]; ta += (sc[p] + 127) >> 7; }
    stot = ta;
  }
  __syncthreads();
  start[tid] = sstart[tid];
  const int c = sc[tid], e0 = tid >> 3, e1 = tid & 7;
  for (int i = 0; (i << 7) < c; ++i)
    meta[stile[tid] + i] = make_int4(e0, e1, sstart[tid] + (i << 7), min(128, c - (i << 7)));
  for (int j = stot + tid; j < NMETA; j += 64)
    meta[j] = make_int4(0, 0, 0, 0);
}

// ---------------- kernel 5: route only (no data copy): wsorted/tokord
__global__ __launch_bounds__(128) void route_k(const unsigned char* __restrict__ pairid,
                                               const float2* __restrict__ wpair,
                                               const int* __restrict__ start,
                                               const int* __restrict__ lbase2d,
                                               float2* __restrict__ wsorted,
                                               int* __restrict__ tokord) {
  __shared__ int lcnt[64];
  const int b = blockIdx.x, tid = threadIdx.x;
  if (tid < 64) lcnt[tid] = 0;
  __syncthreads();
  const int t = b * 128 + tid;
  const int p = pairid[t];
  const int rank = atomicAdd(&lcnt[p], 1);       // LDS only
  const int pos = start[p] + lbase2d[b * 64 + p] + rank;
  wsorted[pos] = wpair[t];
  tokord[pos] = t;
}

// ---------------- kernel 6: pair-sparse GEMM, A-resident / W-chunk-streamed.
// Block = 128 tokens x 128 cols (half) x 2 experts. 512 thr (8 waves, 2r x 4c,
// wave tile 64 tok x 32 col). A (30 granules x 128 rows x 16B = 60KB) gathered
// to LDS ONCE; per iter stage one 8KB W chunk (k-pair, both experts, dbuf).
// Bias applied in f32 epilogue. LDS 79.4KB -> 2 blocks/CU.
#define GLDS16(g, l)                                                        \
  __builtin_amdgcn_global_load_lds(                                         \
      (__attribute__((address_space(1))) unsigned int*)(g),                 \
      (__attribute__((address_space(3))) unsigned int*)(l), 16, 0, 0)

__global__ __launch_bounds__(512, 2) void moe_gemm_pair(const unsigned short* __restrict__ xb,
                                                        const unsigned short* __restrict__ Wb,
                                                        const float* __restrict__ ebias,
                                                        const float2* __restrict__ wsorted,
                                                        const int* __restrict__ tokord,
                                                        const int4* __restrict__ meta,
                                                        float* __restrict__ out) {
  extern __shared__ __align__(16) char smem[];
  char* Ab = smem;                       // [granule 30][row 128][16B] = 61440
  char* Wd = smem + 61440;               // dbuf 2 x [g 2][e 2][col 128][16B] = 2x8192
  int* ptok = (int*)(smem + 77824);      // 512 B
  float2* wab = (float2*)(smem + 78336); // 1024 B

  const int4 m = meta[blockIdx.x >> 1];
  const int n = m.w;
  if (n == 0) return;
  const int ch = blockIdx.x & 1;
  const int tid = threadIdx.x, lane = tid & 63, wid = tid >> 6;
  const int wr = wid >> 2, wcl = wid & 3;        // 2 row x 4 col waves
  const int l31 = lane & 31, hi = lane >> 5;

  if (tid < 128) {
    const int idx = m.z + (tid < n ? tid : n - 1);
    ptok[tid] = tokord[idx];
    wab[tid] = wsorted[idx];
  }
  __syncthreads();

  // W stage geometry: thread tid = g*256 + e*128 + col  (one GLDS16 per chunk)
  const int se = (tid >> 7) & 1;
  const char* wsrc = (const char*)Wb
      + (size_t)((se ? m.y : m.x) * 256 + ch * 128 + (tid & 127)) * 512
      + (tid >> 8) * 16;

  // gather-stage A once: i = g*128 + row, i < 3840
#pragma unroll
  for (int j = 0; j < 7; ++j) {
    const int i = j * 512 + tid;
    GLDS16((const char*)xb + (size_t)ptok[i & 127] * 512 + (i >> 7) * 16, Ab + i * 16);
  }
  if (tid < 256) {
    const int i = 3584 + tid;
    GLDS16((const char*)xb + (size_t)ptok[i & 127] * 512 + (i >> 7) * 16, Ab + i * 16);
  }
  GLDS16(wsrc, Wd + tid * 16);                   // W chunk 0
  __syncthreads();

  f32x16 acc[2][2] = {};                          // [expert][row-frag]

  for (int it = 0; it < 15; ++it) {              // 15 k-pairs (K=240)
    const int buf = it & 1;
    if (it < 14) GLDS16(wsrc + (it + 1) * 32, Wd + ((buf ^ 1) << 13) + tid * 16);
    const char* Ar = Ab + ((2 * it + hi) << 11); // granule stride 2048
    const char* Wg = Wd + (buf << 13) + (hi << 12) + ((wcl * 32 + l31) << 4);
    U16B a0, a1, b0, b1;
    a0.u = *(const uint4*)(Ar + ((wr * 64 + l31) << 4));
    a1.u = *(const uint4*)(Ar + ((wr * 64 + 32 + l31) << 4));
    b0.u = *(const uint4*)(Wg);                  // expert m.x
    b1.u = *(const uint4*)(Wg + 2048);           // expert m.y
    acc[0][0] = __builtin_amdgcn_mfma_f32_32x32x16_bf16(a0.v, b0.v, acc[0][0], 0, 0, 0);
    acc[0][1] = __builtin_amdgcn_mfma_f32_32x32x16_bf16(a1.v, b0.v, acc[0][1], 0, 0, 0);
    acc[1][0] = __builtin_amdgcn_mfma_f32_32x32x16_bf16(a0.v, b1.v, acc[1][0], 0, 0, 0);
    acc[1][1] = __builtin_amdgcn_mfma_f32_32x32x16_bf16(a1.v, b1.v, acc[1][1], 0, 0, 0);
    __syncthreads();     // prefetch drained + buf released; 2nd block covers stall
  }

  // epilogue: out[tok, col] = wa*(P_A + b_A[col]) + wb*(P_B + b_B[col])
  const int col = ch * 128 + wcl * 32 + l31;
  if (col < DIM) {
    const float be0 = ebias[m.x * DIM + col];
    const float be1 = ebias[m.y * DIM + col];
#pragma unroll
    for (int af = 0; af < 2; ++af) {
#pragma unroll
      for (int r = 0; r < 16; ++r) {
        const int rw = wr * 64 + af * 32 + (r & 3) + ((r >> 2) << 3) + (hi << 2);
        if (rw < n) {
          const float2 w2 = wab[rw];
          out[(size_t)ptok[rw] * DIM + col] =
              w2.x * (acc[0][af][r] + be0) + w2.y * (acc[1][af][r] + be1);
        }
      }
    }
  }
}

extern "C" void kernel_launch(void* const* d_in, const int* in_sizes, int n_in,
                              void* d_out, int out_size, void* d_ws, size_t ws_size,
                              hipStream_t stream) {
  const float* x  = (const float*)d_in[0];
  const float* gw = (const float*)d_in[1];
  const float* gb = (const float*)d_in[2];
  const float* ew = (const float*)d_in[3];
  const float* eb = (const float*)d_in[4];
  float* out = (float*)d_out;

  // workspace layout (~36.3 MB)
  char* ws = (char*)d_ws;
  unsigned short* Wb   = (unsigned short*)ws;                          // 1 MB
  unsigned short* xb   = (unsigned short*)(ws + 1048576);              // 32 MB (unsorted bf16 [NTOK][256])
  float2*         wpr  = (float2*)(ws + 34603008);                     // 512 KB
  float2*         wsr  = (float2*)(ws + 35127296);                     // 512 KB
  int*            tord = (int*)(ws + 35651584);                        // 256 KB
  unsigned char*  pid  = (unsigned char*)(ws + 35913728);              // 64 KB
  int*            h2d  = (int*)(ws + 35979264);                        // 128 KB
  int*            lb2d = (int*)(ws + 36110336);                        // 128 KB
  int*            cnt  = (int*)(ws + 36241408);                        // 256 B
  int*            strt = (int*)(ws + 36241664);                        // 256 B
  int4*           meta = (int4*)(ws + 36241920);                       // 9.2 KB

  hipFuncSetAttribute((const void*)moe_gemm_pair, hipFuncAttributeMaxDynamicSharedMemorySize, 79360);

  prep_w<<<512, 256, 0, stream>>>(ew, eb, Wb);
  gating<<<NGB, 512, 0, stream>>>(x, gw, gb, xb, pid, wpr, h2d);
  scan1_k<<<64, NGB, 0, stream>>>(h2d, lb2d, cnt);
  scan2_k<<<1, 64, 0, stream>>>(cnt, strt, meta);
  route_k<<<NGB, 128, 0, stream>>>(pid, wpr, strt, lb2d, wsr, tord);
  moe_gemm_pair<<<2 * NMETA, 512, 79360, stream>>>(xb, Wb, eb, wsr, tord, meta, out);
}